// Round 11
// baseline (703.247 us; speedup 1.0000x reference)
//
#include <hip/hip_runtime.h>
#include <hip/hip_cooperative_groups.h>

namespace cg = cooperative_groups;

#define NV2 163842
#define NV1 40962
#define NV0 10242

using u32 = unsigned int;
using u16 = unsigned short;

typedef __attribute__((ext_vector_type(8))) short bf16x8;
typedef __attribute__((ext_vector_type(4))) float f32x4;
typedef __attribute__((ext_vector_type(4))) u32 u32x4;

// RNE float->bf16 bits
__device__ __forceinline__ u16 f2bf(float f) {
  u32 u = __float_as_uint(f);
  return (u16)((u + 0x7FFFu + ((u >> 16) & 1u)) >> 16);
}
__device__ __forceinline__ void unpack8(uint4 u, float* f) {
  f[0] = __uint_as_float(u.x << 16); f[1] = __uint_as_float(u.x & 0xFFFF0000u);
  f[2] = __uint_as_float(u.y << 16); f[3] = __uint_as_float(u.y & 0xFFFF0000u);
  f[4] = __uint_as_float(u.z << 16); f[5] = __uint_as_float(u.z & 0xFFFF0000u);
  f[6] = __uint_as_float(u.w << 16); f[7] = __uint_as_float(u.w & 0xFFFF0000u);
}
__device__ __forceinline__ uint4 pack8(const float* f) {
  uint4 o;
  o.x = (u32)f2bf(f[0]) | ((u32)f2bf(f[1]) << 16);
  o.y = (u32)f2bf(f[2]) | ((u32)f2bf(f[3]) << 16);
  o.z = (u32)f2bf(f[4]) | ((u32)f2bf(f[5]) << 16);
  o.w = (u32)f2bf(f[6]) | ((u32)f2bf(f[7]) << 16);
  return o;
}
// orderable 16-bit encoding of bf16 bits (for atomicMax pooling in high half of u32)
__device__ __forceinline__ u16 enc16(u16 h) {
  return (h & 0x8000u) ? (u16)~h : (u16)(h | 0x8000u);
}
__device__ __forceinline__ u16 dec16(u16 e) {
  return (e & 0x8000u) ? (u16)(e & 0x7FFFu) : (u16)~e;
}

// ---------- weight transform values ----------
__device__ __forceinline__ float enc_w(const float* __restrict__ W, int C, int i) {
  int j = i / (2 * C), k = i % (2 * C);
  float v = W[(size_t)j * 2 * C + k];
  if (k < C) v -= W[(size_t)j * 2 * C + C + k];
  return v;
}
__device__ __forceinline__ float dec_w(const float* __restrict__ W, int C, int COUT, int i) {
  int j = i / C, k = i % C;
  if (j < COUT) return W[(size_t)j * 2 * C + C + k];
  return W[(size_t)(j - COUT) * 2 * C + k] - W[(size_t)(j - COUT) * 2 * C + C + k];
}

struct MegaArgs {
  const float* features;
  const int* src2; const int* src1; const int* src0;
  const int* p21; const int* p10;
  const float* w_enc0; const float* b_enc0;
  const float* w_enc1; const float* b_enc1;
  const float* w_enc2; const float* b_enc2;
  const float* w_dec0; const float* b_dec0;
  const float* w_dec1; const float* b_dec1;
  u16* featb; u16* f2b; u16* f1pb; u16* f1b; u16* f0pb; u16* f0b;
  u16* h1b; u16* d1b; u16* h2b; u16* z1b; u16* z2b;
  u16* We0; u16* We1; u16* We2; u16* Wd0; u16* Wd1;
  u32* pb1; u32* pb0;
  float* out;
};

// ---------- phase 1: cvt input to bf16, zero pool buffers, 5 weight preps ----------
__device__ __forceinline__ void phase_prep(const MegaArgs& A) {
  const long n_cvt = (long)NV2 * 16;
  const long n_pb1 = (long)NV1 * 32;
  const long n_pb0 = (long)NV0 * 64;
  const long total = n_cvt + n_pb1 + n_pb0 +
                     32 * 32 + 64 * 64 + 128 * 128 + 128 * 192 + 64 * 96;
  for (long i0 = (long)blockIdx.x * 256 + threadIdx.x; i0 < total;
       i0 += (long)gridDim.x * 256) {
    long i = i0;
    if (i < n_cvt) { A.featb[i] = f2bf(A.features[i]); continue; }
    i -= n_cvt;
    if (i < n_pb1) { A.pb1[i] = 0u; continue; }
    i -= n_pb1;
    if (i < n_pb0) { A.pb0[i] = 0u; continue; }
    i -= n_pb0;
    if (i < 32 * 32)   { A.We0[i] = f2bf(enc_w(A.w_enc0, 16, (int)i)); continue; }
    i -= 32 * 32;
    if (i < 64 * 64)   { A.We1[i] = f2bf(enc_w(A.w_enc1, 32, (int)i)); continue; }
    i -= 64 * 64;
    if (i < 128 * 128) { A.We2[i] = f2bf(enc_w(A.w_enc2, 64, (int)i)); continue; }
    i -= 128 * 128;
    if (i < 128 * 192) { A.Wd0[i] = f2bf(dec_w(A.w_dec0, 192, 64, (int)i)); continue; }
    i -= 128 * 192;
    if (i < 64 * 96)   { A.Wd1[i] = f2bf(dec_w(A.w_dec1, 96, 32, (int)i)); continue; }
  }
}

// ---------- pool decode: parent value = max(tail-atomics value, parent's own row) ----
__device__ __forceinline__ void phase_pool_decode(const u32* __restrict__ buf,
                                                  const u16* __restrict__ own,
                                                  u16* __restrict__ outbf, int n) {
  for (int i = blockIdx.x * 256 + threadIdx.x; i < n; i += gridDim.x * 256) {
    u16 e = (u16)(buf[i] >> 16);
    u16 eo = enc16(own[i]);
    outbf[i] = dec16(e > eo ? e : eo);
  }
}

// ---------- encoder GEMM, gather fused into A-operand, tail pooling in epilogue ----
template <int C, int COUT, bool POOL>
__device__ __forceinline__ void phase_gemm_enc(
    const u16* __restrict__ fb, const int* __restrict__ src,
    const u16* __restrict__ Wt, const float* __restrict__ bias,
    u16* __restrict__ outb, u32* __restrict__ pb,
    const int* __restrict__ pmap, int nparent, int nv) {
  constexpr int K = 2 * C;
  constexpr int NT = COUT / 16;
  const int w = threadIdx.x >> 6, lane = threadIdx.x & 63;
  const int lr = lane & 15, lg = lane >> 4;
  const int ntiles = (nv + 63) >> 6;
  for (int t = blockIdx.x; t < ntiles; t += gridDim.x) {
    const int vbase = t * 64 + w * 16;
    int arow = vbase + lr; if (arow >= nv) arow = nv - 1;

    int sidx[6];
#pragma unroll
    for (int kk = 0; kk < 6; ++kk) sidx[kk] = src[(size_t)arow * 6 + kk];

    f32x4 acc[NT] = {};
#pragma unroll
    for (int kt = 0; kt < K; kt += 32) {
      const int k = kt + lg * 8;
      bf16x8 a;
      if (k < C) {
        a = *(const bf16x8*)&fb[(size_t)arow * C + k];
      } else {
        const int c0 = k - C;
        float s[8] = {0.f, 0.f, 0.f, 0.f, 0.f, 0.f, 0.f, 0.f};
#pragma unroll
        for (int kk = 0; kk < 6; ++kk) {
          float nb[8];
          unpack8(*(const uint4*)&fb[(size_t)sidx[kk] * C + c0], nb);
#pragma unroll
          for (int j = 0; j < 8; ++j) s[j] += nb[j];
        }
#pragma unroll
        for (int j = 0; j < 8; ++j) s[j] *= (1.f / 6.f);
        uint4 p = pack8(s);
        a = *(bf16x8*)&p;
      }
#pragma unroll
      for (int nt = 0; nt < NT; ++nt) {
        bf16x8 b = *(const bf16x8*)&Wt[(size_t)(nt * 16 + lr) * K + k];
        acc[nt] = __builtin_amdgcn_mfma_f32_16x16x32_bf16(a, b, acc[nt], 0, 0, 0);
      }
    }

    int prow[4];
    if constexpr (POOL) {
#pragma unroll
      for (int r = 0; r < 4; ++r) {
        int v = vbase + lg * 4 + r;
        prow[r] = (v < nv && v >= nparent) ? pmap[v] : -1;
      }
    }
#pragma unroll
    for (int nt = 0; nt < NT; ++nt) {
#pragma unroll
      for (int r = 0; r < 4; ++r) {
        int v = vbase + lg * 4 + r;
        if (v < nv) {
          int n = nt * 16 + lr;
          float y = acc[nt][r] + bias[n];
          y = (y >= 0.f) ? y : 0.3f * y;
          u16 hb = f2bf(y);
          outb[(size_t)v * COUT + n] = hb;
          if constexpr (POOL)
            if (prow[r] >= 0)
              atomicMax(&pb[(size_t)prow[r] * COUT + n], ((u32)enc16(hb)) << 16);
        }
      }
    }
  }
}

// ---------- decoder GEMM (concat fused): [h|z] = [Ab[map[v]] | Bb[v]] @ Wt^T ----------
template <int CA, int CB, int COUT>
__device__ __forceinline__ void phase_gemm_dec(
    const u16* __restrict__ Ab, const int* __restrict__ map,
    const u16* __restrict__ Bb, const u16* __restrict__ Wt,
    u16* __restrict__ h, u16* __restrict__ zb, int nv) {
  constexpr int K = CA + CB;
  constexpr int N = 2 * COUT;
  constexpr int NT = N / 16;
  const int w = threadIdx.x >> 6, lane = threadIdx.x & 63;
  const int lr = lane & 15, lg = lane >> 4;
  const int ntiles = (nv + 63) >> 6;
  for (int t = blockIdx.x; t < ntiles; t += gridDim.x) {
    const int vbase = t * 64 + w * 16;
    int arow = vbase + lr; if (arow >= nv) arow = nv - 1;
    const int m = map[arow];

    f32x4 acc[NT] = {};
#pragma unroll
    for (int kt = 0; kt < K; kt += 32) {
      int k = kt + lg * 8;
      bf16x8 a = (k < CA) ? *(const bf16x8*)&Ab[(size_t)m * CA + k]
                          : *(const bf16x8*)&Bb[(size_t)arow * CB + (k - CA)];
#pragma unroll
      for (int nt = 0; nt < NT; ++nt) {
        bf16x8 b = *(const bf16x8*)&Wt[(size_t)(nt * 16 + lr) * K + k];
        acc[nt] = __builtin_amdgcn_mfma_f32_16x16x32_bf16(a, b, acc[nt], 0, 0, 0);
      }
    }
#pragma unroll
    for (int nt = 0; nt < NT; ++nt) {
#pragma unroll
      for (int r = 0; r < 4; ++r) {
        int v = vbase + lg * 4 + r;
        if (v < nv) {
          int n = nt * 16 + lr;
          u16 val = f2bf(acc[nt][r]);
          if (n < COUT) h[(size_t)v * COUT + n] = val;
          else          __builtin_nontemporal_store(val, &zb[(size_t)v * COUT + (n - COUT)]);
        }
      }
    }
  }
}

// ---------- decoder combine: y = leaky(z + avg6(h) + b) ----------
template <int COUT, bool OUT32, bool OUTB>
__device__ __forceinline__ void phase_combine(
    const u16* __restrict__ h, const u16* __restrict__ zb,
    const int* __restrict__ src, const float* __restrict__ bias,
    float* __restrict__ out32, u16* __restrict__ outb, int nv) {
  constexpr int TPV = COUT / 8;
  for (int gid = blockIdx.x * 256 + threadIdx.x; gid < nv * TPV;
       gid += gridDim.x * 256) {
    int v = gid / TPV, c0 = (gid % TPV) * 8;
    const int* __restrict__ sp = src + (size_t)v * 6;
    float s[8] = {0.f, 0.f, 0.f, 0.f, 0.f, 0.f, 0.f, 0.f};
#pragma unroll
    for (int k = 0; k < 6; ++k) {
      float nb[8];
      unpack8(*(const uint4*)&h[(size_t)sp[k] * COUT + c0], nb);
#pragma unroll
      for (int j = 0; j < 8; ++j) s[j] += nb[j];
    }
    constexpr float inv6 = 1.f / 6.f;
    float zl[8];
    {
      u32x4 zq = __builtin_nontemporal_load((const u32x4*)&zb[(size_t)v * COUT + c0]);
      uint4 zu; zu.x = zq.x; zu.y = zq.y; zu.z = zq.z; zu.w = zq.w;
      unpack8(zu, zl);
    }
    float4 b0 = *(const float4*)&bias[c0];
    float4 b1 = *(const float4*)&bias[c0 + 4];
    float y[8];
    y[0] = zl[0] + s[0] * inv6 + b0.x; y[1] = zl[1] + s[1] * inv6 + b0.y;
    y[2] = zl[2] + s[2] * inv6 + b0.z; y[3] = zl[3] + s[3] * inv6 + b0.w;
    y[4] = zl[4] + s[4] * inv6 + b1.x; y[5] = zl[5] + s[5] * inv6 + b1.y;
    y[6] = zl[6] + s[6] * inv6 + b1.z; y[7] = zl[7] + s[7] * inv6 + b1.w;
#pragma unroll
    for (int j = 0; j < 8; ++j) y[j] = (y[j] >= 0.f) ? y[j] : 0.3f * y[j];
    if constexpr (OUT32) {
      float* p = &out32[(size_t)v * COUT + c0];
#pragma unroll
      for (int j = 0; j < 8; ++j) __builtin_nontemporal_store(y[j], p + j);
    }
    if constexpr (OUTB) *(uint4*)&outb[(size_t)v * COUT + c0] = pack8(y);
  }
}

// ---------- the mega-kernel: 10 phases, 9 grid syncs, 1 dispatch ----------
__global__ __launch_bounds__(256, 4) void mega_k(MegaArgs A) {
  cg::grid_group g = cg::this_grid();
  phase_prep(A);
  g.sync();
  phase_gemm_enc<16, 32, true>(A.featb, A.src2, A.We0, A.b_enc0, A.f2b,
                               A.pb1, A.p21, NV1, NV2);
  g.sync();
  phase_pool_decode(A.pb1, A.f2b, A.f1pb, NV1 * 32);
  g.sync();
  phase_gemm_enc<32, 64, true>(A.f1pb, A.src1, A.We1, A.b_enc1, A.f1b,
                               A.pb0, A.p10, NV0, NV1);
  g.sync();
  phase_pool_decode(A.pb0, A.f1b, A.f0pb, NV0 * 64);
  g.sync();
  phase_gemm_enc<64, 128, false>(A.f0pb, A.src0, A.We2, A.b_enc2, A.f0b,
                                 nullptr, nullptr, 0, NV0);
  g.sync();
  phase_gemm_dec<128, 64, 64>(A.f0b, A.p10, A.f1b, A.Wd0, A.h1b, A.z1b, NV1);
  g.sync();
  phase_combine<64, false, true>(A.h1b, A.z1b, A.src1, A.b_dec0, nullptr, A.d1b, NV1);
  g.sync();
  phase_gemm_dec<64, 32, 32>(A.d1b, A.p21, A.f2b, A.Wd1, A.h2b, A.z2b, NV2);
  g.sync();
  phase_combine<32, true, false>(A.h2b, A.z2b, A.src2, A.b_dec1, A.out, nullptr, NV2);
}

extern "C" void kernel_launch(void* const* d_in, const int* in_sizes, int n_in,
                              void* d_out, int out_size, void* d_ws, size_t ws_size,
                              hipStream_t stream) {
  // ---- linear workspace layout (~70 MB, no aliasing; all offsets 16B-aligned) ----
  u16* featb = (u16*)d_ws;                      // [NV2,16]
  u16* f2b   = featb + (size_t)NV2 * 16;        // [NV2,32]
  u16* f1pb  = f2b   + (size_t)NV2 * 32;        // [NV1,32]
  u16* f1b   = f1pb  + (size_t)NV1 * 32;        // [NV1,64]
  u16* f0pb  = f1b   + (size_t)NV1 * 64;        // [NV0,64]
  u16* f0b   = f0pb  + (size_t)NV0 * 64;        // [NV0,128]
  u16* h1b   = f0b   + (size_t)NV0 * 128;       // [NV1,64]
  u16* d1b   = h1b   + (size_t)NV1 * 64;        // [NV1,64]
  u16* h2b   = d1b   + (size_t)NV1 * 64;        // [NV2,32]
  u16* z1b   = h2b   + (size_t)NV2 * 32;        // [NV1,64]
  u16* z2b   = z1b   + (size_t)NV1 * 64;        // [NV2,32]
  u16* We0   = z2b   + (size_t)NV2 * 32;        // [32,32]
  u16* We1   = We0 + 32 * 32;                   // [64,64]
  u16* We2   = We1 + 64 * 64;                   // [128,128]
  u16* Wd0   = We2 + 128 * 128;                 // [128,192]
  u16* Wd1   = Wd0 + 128 * 192;                 // [64,96]
  u32* pb1   = (u32*)(Wd1 + 64 * 96);           // [NV1,32]
  u32* pb0   = pb1 + (size_t)NV1 * 32;          // [NV0,64]

  MegaArgs A;
  A.features = (const float*)d_in[0];
  A.src2 = (const int*)d_in[1];
  A.src1 = (const int*)d_in[3];
  A.src0 = (const int*)d_in[5];
  A.p21 = (const int*)d_in[7];
  A.p10 = (const int*)d_in[8];
  A.w_enc0 = (const float*)d_in[9];  A.b_enc0 = (const float*)d_in[10];
  A.w_enc1 = (const float*)d_in[11]; A.b_enc1 = (const float*)d_in[12];
  A.w_enc2 = (const float*)d_in[13]; A.b_enc2 = (const float*)d_in[14];
  A.w_dec0 = (const float*)d_in[15]; A.b_dec0 = (const float*)d_in[16];
  A.w_dec1 = (const float*)d_in[17]; A.b_dec1 = (const float*)d_in[18];
  A.featb = featb; A.f2b = f2b; A.f1pb = f1pb; A.f1b = f1b; A.f0pb = f0pb;
  A.f0b = f0b; A.h1b = h1b; A.d1b = d1b; A.h2b = h2b; A.z1b = z1b; A.z2b = z2b;
  A.We0 = We0; A.We1 = We1; A.We2 = We2; A.Wd0 = Wd0; A.Wd1 = Wd1;
  A.pb1 = pb1; A.pb0 = pb0;
  A.out = (float*)d_out;

  // Size the cooperative grid from actual occupancy (grid-stride phases make
  // correctness independent of grid size; deterministic per-run).
  int maxb = 0;
  (void)hipOccupancyMaxActiveBlocksPerMultiprocessor(&maxb, mega_k, 256, 0);
  if (maxb < 1) maxb = 1;
  long nblk = (long)maxb * 256;           // 256 CUs on MI355X
  if (nblk > 2048) nblk = 2048;
  void* kargs[] = { (void*)&A };
  (void)hipLaunchCooperativeKernel(mega_k, dim3((u32)nblk), dim3(256),
                                   kargs, 0, stream);
}

// Round 12
// 131.599 us; speedup vs baseline: 5.3438x; 5.3438x over previous
//
#include <hip/hip_runtime.h>

#define NV2 163842
#define NV1 40962
#define NV0 10242

using u32 = unsigned int;
using u16 = unsigned short;

typedef __attribute__((ext_vector_type(8))) short bf16x8;
typedef __attribute__((ext_vector_type(4))) float f32x4;

// RNE float->bf16 bits
__device__ __forceinline__ u16 f2bf(float f) {
  u32 u = __float_as_uint(f);
  return (u16)((u + 0x7FFFu + ((u >> 16) & 1u)) >> 16);
}
__device__ __forceinline__ void unpack8(uint4 u, float* f) {
  f[0] = __uint_as_float(u.x << 16); f[1] = __uint_as_float(u.x & 0xFFFF0000u);
  f[2] = __uint_as_float(u.y << 16); f[3] = __uint_as_float(u.y & 0xFFFF0000u);
  f[4] = __uint_as_float(u.z << 16); f[5] = __uint_as_float(u.z & 0xFFFF0000u);
  f[6] = __uint_as_float(u.w << 16); f[7] = __uint_as_float(u.w & 0xFFFF0000u);
}
__device__ __forceinline__ uint4 pack8(const float* f) {
  uint4 o;
  o.x = (u32)f2bf(f[0]) | ((u32)f2bf(f[1]) << 16);
  o.y = (u32)f2bf(f[2]) | ((u32)f2bf(f[3]) << 16);
  o.z = (u32)f2bf(f[4]) | ((u32)f2bf(f[5]) << 16);
  o.w = (u32)f2bf(f[6]) | ((u32)f2bf(f[7]) << 16);
  return o;
}
// orderable 16-bit encoding of bf16 bits (for atomicMax pooling in high half of u32)
__device__ __forceinline__ u16 enc16(u16 h) {
  return (h & 0x8000u) ? (u16)~h : (u16)(h | 0x8000u);
}
__device__ __forceinline__ u16 dec16(u16 e) {
  return (e & 0x8000u) ? (u16)(e & 0x7FFFu) : (u16)~e;
}

// ---------- weight transform values ----------
__device__ __forceinline__ float enc_w(const float* __restrict__ W, int C, int i) {
  int j = i / (2 * C), k = i % (2 * C);
  float v = W[(size_t)j * 2 * C + k];
  if (k < C) v -= W[(size_t)j * 2 * C + C + k];
  return v;
}
__device__ __forceinline__ float dec_w(const float* __restrict__ W, int C, int COUT, int i) {
  int j = i / C, k = i % C;
  if (j < COUT) return W[(size_t)j * 2 * C + C + k];
  return W[(size_t)(j - COUT) * 2 * C + k] - W[(size_t)(j - COUT) * 2 * C + C + k];
}

// ---------- one-shot prep: cvt input to bf16, zero pool buffers, 5 weight preps ----------
__global__ __launch_bounds__(256) void prep_all_k(
    const float* __restrict__ features, u16* __restrict__ featb,
    u32* __restrict__ pb1, u32* __restrict__ pb0,
    const float* __restrict__ w_enc0, u16* __restrict__ We0,
    const float* __restrict__ w_enc1, u16* __restrict__ We1,
    const float* __restrict__ w_enc2, u16* __restrict__ We2,
    const float* __restrict__ w_dec0, u16* __restrict__ Wd0,
    const float* __restrict__ w_dec1, u16* __restrict__ Wd1) {
  long i = (long)blockIdx.x * 256 + threadIdx.x;
  const long n_cvt = (long)NV2 * 16;
  if (i < n_cvt) { featb[i] = f2bf(features[i]); return; }
  i -= n_cvt;
  const long n_pb1 = (long)NV1 * 32;
  if (i < n_pb1) { pb1[i] = 0u; return; }
  i -= n_pb1;
  const long n_pb0 = (long)NV0 * 64;
  if (i < n_pb0) { pb0[i] = 0u; return; }
  i -= n_pb0;
  if (i < 32 * 32)   { We0[i] = f2bf(enc_w(w_enc0, 16, (int)i)); return; }
  i -= 32 * 32;
  if (i < 64 * 64)   { We1[i] = f2bf(enc_w(w_enc1, 32, (int)i)); return; }
  i -= 64 * 64;
  if (i < 128 * 128) { We2[i] = f2bf(enc_w(w_enc2, 64, (int)i)); return; }
  i -= 128 * 128;
  if (i < 128 * 192) { Wd0[i] = f2bf(dec_w(w_dec0, 192, 64, (int)i)); return; }
  i -= 128 * 192;
  if (i < 64 * 96)   { Wd1[i] = f2bf(dec_w(w_dec1, 96, 32, (int)i)); return; }
}

// ---------- pool decode: parent value = max(tail-atomics value, parent's own row) ----
__global__ __launch_bounds__(256) void pool_decode_k(const u32* __restrict__ buf,
                                                     const u16* __restrict__ own,
                                                     u16* __restrict__ outbf, int n) {
  int i = blockIdx.x * 256 + threadIdx.x;
  if (i < n) {
    u16 e = (u16)(buf[i] >> 16);
    u16 eo = enc16(own[i]);
    outbf[i] = dec16(e > eo ? e : eo);
  }
}

// ---------- encoder GEMM, gather fused into A-operand, tail pooling in epilogue ----
template <int C, int COUT, bool POOL>
__global__ __launch_bounds__(256) void gemm_enc_k(
    const u16* __restrict__ fb, const int* __restrict__ src,
    const u16* __restrict__ Wt, const float* __restrict__ bias,
    u16* __restrict__ outb, u32* __restrict__ pb,
    const int* __restrict__ pmap, int nparent, int nv) {
  constexpr int K = 2 * C;
  constexpr int NT = COUT / 16;
  const int w = threadIdx.x >> 6, lane = threadIdx.x & 63;
  const int lr = lane & 15, lg = lane >> 4;
  const int vbase = blockIdx.x * 64 + w * 16;
  int arow = vbase + lr; if (arow >= nv) arow = nv - 1;

  int sidx[6];
#pragma unroll
  for (int kk = 0; kk < 6; ++kk) sidx[kk] = src[(size_t)arow * 6 + kk];

  f32x4 acc[NT] = {};
#pragma unroll
  for (int kt = 0; kt < K; kt += 32) {
    const int k = kt + lg * 8;
    bf16x8 a;
    if (k < C) {
      a = *(const bf16x8*)&fb[(size_t)arow * C + k];
    } else {
      const int c0 = k - C;
      float s[8] = {0.f, 0.f, 0.f, 0.f, 0.f, 0.f, 0.f, 0.f};
#pragma unroll
      for (int kk = 0; kk < 6; ++kk) {
        float nb[8];
        unpack8(*(const uint4*)&fb[(size_t)sidx[kk] * C + c0], nb);
#pragma unroll
        for (int j = 0; j < 8; ++j) s[j] += nb[j];
      }
#pragma unroll
      for (int j = 0; j < 8; ++j) s[j] *= (1.f / 6.f);
      uint4 p = pack8(s);
      a = *(bf16x8*)&p;
    }
#pragma unroll
    for (int nt = 0; nt < NT; ++nt) {
      bf16x8 b = *(const bf16x8*)&Wt[(size_t)(nt * 16 + lr) * K + k];
      acc[nt] = __builtin_amdgcn_mfma_f32_16x16x32_bf16(a, b, acc[nt], 0, 0, 0);
    }
  }

  int prow[4];
  if constexpr (POOL) {
#pragma unroll
    for (int r = 0; r < 4; ++r) {
      int v = vbase + lg * 4 + r;
      prow[r] = (v < nv && v >= nparent) ? pmap[v] : -1;
    }
  }
#pragma unroll
  for (int nt = 0; nt < NT; ++nt) {
#pragma unroll
    for (int r = 0; r < 4; ++r) {
      int v = vbase + lg * 4 + r;
      if (v < nv) {
        int n = nt * 16 + lr;
        float y = acc[nt][r] + bias[n];
        y = (y >= 0.f) ? y : 0.3f * y;
        u16 hb = f2bf(y);
        outb[(size_t)v * COUT + n] = hb;
        if constexpr (POOL)
          if (prow[r] >= 0)
            atomicMax(&pb[(size_t)prow[r] * COUT + n], ((u32)enc16(hb)) << 16);
      }
    }
  }
}

// ---------- decoder GEMM (concat fused): [h|z] = [Ab[map[v]] | Bb[v]] @ Wt^T ----------
template <int CA, int CB, int COUT>
__global__ __launch_bounds__(256) void gemm_dec_k(
    const u16* __restrict__ Ab, const int* __restrict__ map,
    const u16* __restrict__ Bb, const u16* __restrict__ Wt,
    u16* __restrict__ h, u16* __restrict__ zb, int nv) {
  constexpr int K = CA + CB;
  constexpr int N = 2 * COUT;
  constexpr int NT = N / 16;
  const int w = threadIdx.x >> 6, lane = threadIdx.x & 63;
  const int lr = lane & 15, lg = lane >> 4;
  const int vbase = blockIdx.x * 64 + w * 16;
  int arow = vbase + lr; if (arow >= nv) arow = nv - 1;
  const int m = map[arow];

  f32x4 acc[NT] = {};
#pragma unroll
  for (int kt = 0; kt < K; kt += 32) {
    int k = kt + lg * 8;
    bf16x8 a = (k < CA) ? *(const bf16x8*)&Ab[(size_t)m * CA + k]
                        : *(const bf16x8*)&Bb[(size_t)arow * CB + (k - CA)];
#pragma unroll
    for (int nt = 0; nt < NT; ++nt) {
      bf16x8 b = *(const bf16x8*)&Wt[(size_t)(nt * 16 + lr) * K + k];
      acc[nt] = __builtin_amdgcn_mfma_f32_16x16x32_bf16(a, b, acc[nt], 0, 0, 0);
    }
  }
#pragma unroll
  for (int nt = 0; nt < NT; ++nt) {
#pragma unroll
    for (int r = 0; r < 4; ++r) {
      int v = vbase + lg * 4 + r;
      if (v < nv) {
        int n = nt * 16 + lr;
        u16 val = f2bf(acc[nt][r]);
        if (n < COUT) h[(size_t)v * COUT + n] = val;
        else          zb[(size_t)v * COUT + (n - COUT)] = val;
      }
    }
  }
}

// ---------- decoder combine: y = leaky(z + avg6(h) + b) ----------
template <int COUT, bool OUT32, bool OUTB>
__global__ __launch_bounds__(256) void combine_k(
    const u16* __restrict__ h, const u16* __restrict__ zb,
    const int* __restrict__ src, const float* __restrict__ bias,
    float* __restrict__ out32, u16* __restrict__ outb, int nv) {
  constexpr int TPV = COUT / 8;
  int gid = blockIdx.x * 256 + threadIdx.x;
  if (gid >= nv * TPV) return;
  int v = gid / TPV, c0 = (gid % TPV) * 8;
  const int* __restrict__ sp = src + (size_t)v * 6;
  float s[8] = {0.f, 0.f, 0.f, 0.f, 0.f, 0.f, 0.f, 0.f};
#pragma unroll
  for (int k = 0; k < 6; ++k) {
    float nb[8];
    unpack8(*(const uint4*)&h[(size_t)sp[k] * COUT + c0], nb);
#pragma unroll
    for (int j = 0; j < 8; ++j) s[j] += nb[j];
  }
  constexpr float inv6 = 1.f / 6.f;
  float zl[8];
  unpack8(*(const uint4*)&zb[(size_t)v * COUT + c0], zl);
  float4 b0 = *(const float4*)&bias[c0];
  float4 b1 = *(const float4*)&bias[c0 + 4];
  float y[8];
  y[0] = zl[0] + s[0] * inv6 + b0.x; y[1] = zl[1] + s[1] * inv6 + b0.y;
  y[2] = zl[2] + s[2] * inv6 + b0.z; y[3] = zl[3] + s[3] * inv6 + b0.w;
  y[4] = zl[4] + s[4] * inv6 + b1.x; y[5] = zl[5] + s[5] * inv6 + b1.y;
  y[6] = zl[6] + s[6] * inv6 + b1.z; y[7] = zl[7] + s[7] * inv6 + b1.w;
#pragma unroll
  for (int j = 0; j < 8; ++j) y[j] = (y[j] >= 0.f) ? y[j] : 0.3f * y[j];
  if constexpr (OUT32) {
    *(float4*)&out32[(size_t)v * COUT + c0]     = make_float4(y[0], y[1], y[2], y[3]);
    *(float4*)&out32[(size_t)v * COUT + c0 + 4] = make_float4(y[4], y[5], y[6], y[7]);
  }
  if constexpr (OUTB) *(uint4*)&outb[(size_t)v * COUT + c0] = pack8(y);
}

extern "C" void kernel_launch(void* const* d_in, const int* in_sizes, int n_in,
                              void* d_out, int out_size, void* d_ws, size_t ws_size,
                              hipStream_t stream) {
  const float* features = (const float*)d_in[0];
  const int* src2 = (const int*)d_in[1];
  const int* src1 = (const int*)d_in[3];
  const int* src0 = (const int*)d_in[5];
  const int* p21 = (const int*)d_in[7];
  const int* p10 = (const int*)d_in[8];
  const float* w_enc0 = (const float*)d_in[9];
  const float* b_enc0 = (const float*)d_in[10];
  const float* w_enc1 = (const float*)d_in[11];
  const float* b_enc1 = (const float*)d_in[12];
  const float* w_enc2 = (const float*)d_in[13];
  const float* b_enc2 = (const float*)d_in[14];
  const float* w_dec0 = (const float*)d_in[15];
  const float* b_dec0 = (const float*)d_in[16];
  const float* w_dec1 = (const float*)d_in[17];
  const float* b_dec1 = (const float*)d_in[18];

  // ---- linear workspace layout (~70 MB, no aliasing; all offsets 16B-aligned) ----
  u16* featb = (u16*)d_ws;                      // [NV2,16]
  u16* f2b   = featb + (size_t)NV2 * 16;        // [NV2,32]
  u16* f1pb  = f2b   + (size_t)NV2 * 32;        // [NV1,32]
  u16* f1b   = f1pb  + (size_t)NV1 * 32;        // [NV1,64]
  u16* f0pb  = f1b   + (size_t)NV1 * 64;        // [NV0,64]
  u16* f0b   = f0pb  + (size_t)NV0 * 64;        // [NV0,128]
  u16* h1b   = f0b   + (size_t)NV0 * 128;       // [NV1,64]
  u16* d1b   = h1b   + (size_t)NV1 * 64;        // [NV1,64]
  u16* h2b   = d1b   + (size_t)NV1 * 64;        // [NV2,32]
  u16* z1b   = h2b   + (size_t)NV2 * 32;        // [NV1,64]
  u16* z2b   = z1b   + (size_t)NV1 * 64;        // [NV2,32]
  u16* We0   = z2b   + (size_t)NV2 * 32;        // [32,32]
  u16* We1   = We0 + 32 * 32;                   // [64,64]
  u16* We2   = We1 + 64 * 64;                   // [128,128]
  u16* Wd0   = We2 + 128 * 128;                 // [128,192]
  u16* Wd1   = Wd0 + 128 * 192;                 // [64,96]
  u32* pb1   = (u32*)(Wd1 + 64 * 96);           // [NV1,32]
  u32* pb0   = pb1 + (size_t)NV1 * 32;          // [NV0,64]
  float* out = (float*)d_out;                   // [NV2,32]

  auto cdiv = [](long long a, long long b) { return (int)((a + b - 1) / b); };

  // ---- 1: prep (cvt + zero pools + weight transforms) ----
  const long prep_n = (long)NV2 * 16 + (long)NV1 * 32 + (long)NV0 * 64 +
                      32 * 32 + 64 * 64 + 128 * 128 + 128 * 192 + 64 * 96;
  prep_all_k<<<cdiv(prep_n, 256), 256, 0, stream>>>(
      features, featb, pb1, pb0, w_enc0, We0, w_enc1, We1, w_enc2, We2,
      w_dec0, Wd0, w_dec1, Wd1);

  // ---- 2: encoder L2 (gather fused; tail of pool 2->1 fused into epilogue) ----
  gemm_enc_k<16, 32, true><<<cdiv(NV2, 64), 256, 0, stream>>>(
      featb, src2, We0, b_enc0, f2b, pb1, p21, NV1, NV2);
  // ---- 3: decode pool 2->1 (max with identity-prefix rows of f2b) ----
  pool_decode_k<<<cdiv((size_t)NV1 * 32, 256), 256, 0, stream>>>(
      pb1, f2b, f1pb, NV1 * 32);
  // ---- 4: encoder L1 (pool 1->0 tail fused) ----
  gemm_enc_k<32, 64, true><<<cdiv(NV1, 64), 256, 0, stream>>>(
      f1pb, src1, We1, b_enc1, f1b, pb0, p10, NV0, NV1);
  // ---- 5: decode pool 1->0 ----
  pool_decode_k<<<cdiv((size_t)NV0 * 64, 256), 256, 0, stream>>>(
      pb0, f1b, f0pb, NV0 * 64);
  // ---- 6: encoder L0 ----
  gemm_enc_k<64, 128, false><<<cdiv(NV0, 64), 256, 0, stream>>>(
      f0pb, src0, We2, b_enc2, f0b, nullptr, nullptr, 0, NV0);
  // ---- 7: decoder L1 GEMM: [h1|z1] = [f0b[p10] | f1b] @ Wd0^T ----
  gemm_dec_k<128, 64, 64><<<cdiv(NV1, 64), 256, 0, stream>>>(
      f0b, p10, f1b, Wd0, h1b, z1b, NV1);
  // ---- 8: decoder L1 combine -> d1b ----
  combine_k<64, false, true><<<cdiv((size_t)NV1 * 8, 256), 256, 0, stream>>>(
      h1b, z1b, src1, b_dec0, nullptr, d1b, NV1);
  // ---- 9: decoder L2 GEMM: [h2|z2] = [d1b[p21] | f2b] @ Wd1^T ----
  gemm_dec_k<64, 32, 32><<<cdiv(NV2, 64), 256, 0, stream>>>(
      d1b, p21, f2b, Wd1, h2b, z2b, NV2);
  // ---- 10: decoder L2 combine -> out ----
  combine_k<32, true, false><<<cdiv((size_t)NV2 * 4, 256), 256, 0, stream>>>(
      h2b, z2b, src2, b_dec1, out, nullptr, NV2);
}